// Round 2
// baseline (4113.096 us; speedup 1.0000x reference)
//
#include <hip/hip_runtime.h>
#include <hip/hip_bf16.h>
#include <math.h>

typedef unsigned short u16;
typedef unsigned int   u32;

#define TILE 16

// ---------------------------------------------------------------------------
// ws layout (float offsets):
//  [0..357)    : the 9 real-basis w3j tensors (see OFF[] below)
//  [368]       : dtype flag (int; 1 = inputs are bf16, 0 = inputs are f32)
//  [384..8576) : Wg1 f32   (8192)
//  [8576..)    : Wg2       (9216)
//  [17792..)   : WU0 (2048) [19840..): WU1 (1024) [20864..): WU2 (512)
//  [21376..)   : WV0 (2048) [23424..): WV1 (1024) [24448..): WV2 (512)
//  [24960..)   : bg1 (64)   [25024..): bg2 (144)  [25168..): C9 (9)
//  [25216..)   : res accumulator (G*9 f32)
// ---------------------------------------------------------------------------
#define WS_FLAG  368
#define WS_WG1   384
#define WS_WG2   8576
#define WS_WU0   17792
#define WS_WU1   19840
#define WS_WU2   20864
#define WS_WV0   21376
#define WS_WV1   23424
#define WS_WV2   24448
#define WS_BG1   24960
#define WS_BG2   25024
#define WS_C9    25168
#define WS_RES   25216

__device__ __forceinline__ float b2f(u16 u){
  return __uint_as_float(((u32)u) << 16);
}
__device__ __forceinline__ float ldconv(const void* p, int i, int isbf){
  return isbf ? b2f(((const u16*)p)[i]) : ((const float*)p)[i];
}

// ---------------------------------------------------------------------------
// dtype detection: sample 1024 u32 words of x_spherical. If buffer is bf16,
// the low u16 of each word is a ~N(0,1) bf16 -> exponent field near 127.
// If buffer is f32, the low u16 is mantissa garbage -> uniform exponent field.
// ---------------------------------------------------------------------------
__global__ void detect_kernel(const u32* __restrict__ words, int* __restrict__ flag){
  int t = threadIdx.x;
  int cnt = 0;
  for (int i = 0; i < 16; i++){
    u32 w = words[t*16 + i];
    u32 e = (w >> 7) & 0xFF;
    cnt += (e >= 117 && e <= 137) ? 1 : 0;
  }
  #pragma unroll
  for (int m = 1; m < 64; m <<= 1) cnt += __shfl_xor(cnt, m, 64);
  if (t == 0) *flag = (cnt > 512) ? 1 : 0;
}

// ---------------------------------------------------------------------------
// Wigner 3j setup (double precision, replicates the reference exactly)
// ---------------------------------------------------------------------------
__device__ double factd(int n){ double r=1.0; for(int i=2;i<=n;++i) r*=(double)i; return r; }

__device__ double su2_cg(int j1,int m1,int j2,int m2,int j3,int m3){
  if (m1+m2 != m3) return 0.0;
  int vmin = max(max(-j1+j2+m3, -j1+m1), 0);
  int vmax = min(min(j2+j3+m1, j3-j1+j2), j3+m3);
  double C = sqrt((2.0*j3+1.0)
      * factd(j3+j1-j2)*factd(j3-j1+j2)*factd(j1+j2-j3)*factd(j3+m3)*factd(j3-m3)
      / (factd(j1+j2+j3+1)*factd(j1-m1)*factd(j1+m1)*factd(j2-m2)*factd(j2+m2)));
  double S = 0.0;
  for (int v=vmin; v<=vmax; ++v){
    double t = factd(j2+j3+m1-v)*factd(j1-m1+v)
             / (factd(v)*factd(j3-j1+j2-v)*factd(j3+m3-v)*factd(v+j1-j2-m3));
    S += ((v+j2+m2)&1) ? -t : t;
  }
  return C*S;
}

__device__ void qmat(int l, double* qre, double* qim){
  int d = 2*l+1;
  for (int i=0;i<d*d;i++){ qre[i]=0.0; qim[i]=0.0; }
  double s = 1.0/sqrt(2.0);
  for (int m=-l; m<0; ++m){
    qre[(l+m)*d + (l-m)] = s;
    qim[(l+m)*d + (l+m)] = -s;
  }
  qre[l*d + l] = 1.0;
  for (int m=1; m<=l; ++m){
    double sgn = (m&1) ? -1.0 : 1.0;
    qre[(l+m)*d + (l+m)] = sgn*s;
    qim[(l+m)*d + (l-m)] = sgn*s;
  }
  double fr, fi;
  switch (l & 3){ case 0: fr=1; fi=0; break; case 1: fr=0; fi=-1; break;
                  case 2: fr=-1; fi=0; break; default: fr=0; fi=1; }
  for (int i=0;i<d*d;i++){
    double a=qre[i], b=qim[i];
    qre[i]=a*fr-b*fi; qim[i]=a*fi+b*fr;
  }
}

__device__ void compute_w3j(int l1,int l2,int l3, float* out){
  int d1=2*l1+1, d2=2*l2+1, d3=2*l3+1;
  double q1r[25],q1i[25],q2r[25],q2i[25],q3r[25],q3i[25];
  qmat(l1,q1r,q1i); qmat(l2,q2r,q2i); qmat(l3,q3r,q3i);
  double cg[125];
  for (int i=0;i<d1;i++)
    for (int k=0;k<d2;k++)
      for (int n=0;n<d3;n++)
        cg[(i*d2+k)*d3+n] = su2_cg(l1,i-l1,l2,k-l2,l3,n-l3);
  double res[125]; double nrm=0.0;
  for (int j=0;j<d1;j++)
    for (int l=0;l<d2;l++)
      for (int m=0;m<d3;m++){
        double ar=0.0;
        for (int i=0;i<d1;i++){
          double a1r=q1r[i*d1+j], a1i=q1i[i*d1+j];
          for (int k=0;k<d2;k++){
            double a2r=q2r[k*d2+l], a2i=q2i[k*d2+l];
            double t12r = a1r*a2r - a1i*a2i;
            double t12i = a1r*a2i + a1i*a2r;
            for (int n=0;n<d3;n++){
              double c = cg[(i*d2+k)*d3+n];
              if (c==0.0) continue;
              double a3r = q3r[n*d3+m], a3i = -q3i[n*d3+m];
              ar += c*(t12r*a3r - t12i*a3i);
            }
          }
        }
        res[(j*d2+l)*d3+m] = ar; nrm += ar*ar;
      }
  nrm = sqrt(nrm);
  int tot = d1*d2*d3;
  for (int x=0;x<tot;x++) out[x] = (float)(res[x]/nrm);
}

__global__ void setup_kernel(float* __restrict__ ws){
  int t = threadIdx.x;
  const int L1[9]={0,0,1,1,1,2,2,2,2};
  const int L2[9]={0,2,1,1,1,0,2,2,2};
  const int L3[9]={0,2,0,1,2,2,0,1,2};
  const int OFF[9]={0,1,26,35,62,107,132,157,232};
  if (t < 9) compute_w3j(L1[t], L2[t], L3[t], ws + OFF[t]);
}

// ---------------------------------------------------------------------------
// Weight canonicalization: everything small -> f32 into ws
// ---------------------------------------------------------------------------
__global__ void convert_weights(
    const void* Wg1, const void* Wg2,
    const void* WU0, const void* WU1, const void* WU2,
    const void* WV0, const void* WV1, const void* WV2,
    const void* bg1, const void* bg2,
    const void* Wp0, const void* Wp1, const void* Wp2,
    float* __restrict__ ws)
{
  const int isbf = ((const int*)ws)[WS_FLAG];
  const int b = blockIdx.x, t = threadIdx.x;
  if (b < 10){
    const void* src[10] = {Wg1,Wg2,WU0,WU1,WU2,WV0,WV1,WV2,bg1,bg2};
    const int   sz[10]  = {8192,9216,2048,1024,512,2048,1024,512,64,144};
    const int   off[10] = {WS_WG1,WS_WG2,WS_WU0,WS_WU1,WS_WU2,WS_WV0,WS_WV1,WS_WV2,WS_BG1,WS_BG2};
    const void* s = src[b]; float* d = ws + off[b]; int n = sz[b];
    for (int i = t; i < n; i += 256) d[i] = ldconv(s, i, isbf);
  } else if (b == 10 && t == 0){
    float* C9 = ws + WS_C9;
    const int l3k[9]  = {0,2,0,1,2,2,0,1,2};
    const int idxk[9] = {0,0,1,0,1,2,2,1,3};
    for (int k=0;k<9;k++){
      int l3 = l3k[k];
      const void* wp = (l3==0) ? Wp0 : (l3==1) ? Wp1 : Wp2;
      float wpv = ldconv(wp, idxk[k], isbf);
      float len = (l3==0) ? 3.f : (l3==1) ? 2.f : 4.f;
      C9[k] = sqrtf((2.f*l3 + 1.f)/16.f) * wpv * rsqrtf(len);
    }
  }
}

// ---------------------------------------------------------------------------
// Main fused kernel: 16 atoms per block, 256 threads (4 waves).
// ---------------------------------------------------------------------------
__device__ __forceinline__ void load8_bf16(const u16* p, float* dst){
  uint4 v = *reinterpret_cast<const uint4*>(p);
  u32 w[4] = {v.x, v.y, v.z, v.w};
  #pragma unroll
  for (int q=0;q<4;q++){
    dst[2*q]   = __uint_as_float((w[q] & 0xffffu) << 16);
    dst[2*q+1] = __uint_as_float(w[q] & 0xffff0000u);
  }
}
__device__ __forceinline__ void load8_f32(const float* p, float* dst){
  float4 v0 = *reinterpret_cast<const float4*>(p);
  float4 v1 = *reinterpret_cast<const float4*>(p+4);
  dst[0]=v0.x; dst[1]=v0.y; dst[2]=v0.z; dst[3]=v0.w;
  dst[4]=v1.x; dst[5]=v1.y; dst[6]=v1.z; dst[7]=v1.w;
}

__global__ __launch_bounds__(256) void main_kernel(
    const int* __restrict__ batch,
    const void* __restrict__ xscv,   // N x 128 (bf16 or f32)
    const void* __restrict__ xspv,   // N x 480 (bf16 or f32)
    const float* __restrict__ ws,
    float* __restrict__ res,
    int N)
{
  __shared__ float s_xsph[TILE][481];
  __shared__ float s_w[TILE][144];
  __shared__ float s_uni[4624];
  __shared__ float s_w3j[357];
  __shared__ float s_bg1[64];
  __shared__ float s_bg2[144];
  __shared__ float s_C[9];
  __shared__ int   s_batch[TILE];

  float (*s_xs)[128] = reinterpret_cast<float(*)[128]>(s_uni);
  float (*s_h1)[64]  = reinterpret_cast<float(*)[64]>(s_uni + 2048);
  float (*s_hU)[144] = reinterpret_cast<float(*)[144]>(s_uni);
  float (*s_hV)[144] = reinterpret_cast<float(*)[144]>(s_uni + 2304);

  const int tid  = threadIdx.x;
  const int wave = tid >> 6;
  const int lane = tid & 63;
  const int n0   = blockIdx.x * TILE;
  const int isbf = ((const int*)ws)[WS_FLAG];

  const float* wsWg1 = ws + WS_WG1;
  const float* wsWg2 = ws + WS_WG2;
  const float* wsWU0 = ws + WS_WU0;
  const float* wsWU1 = ws + WS_WU1;
  const float* wsWU2 = ws + WS_WU2;
  const float* wsWV0 = ws + WS_WV0;
  const float* wsWV1 = ws + WS_WV1;
  const float* wsWV2 = ws + WS_WV2;

  // ---- staging -----------------------------------------------------------
  if (tid < TILE){ int n = n0 + tid; s_batch[tid] = (n < N) ? batch[n] : -1; }
  if (tid < 64)  s_bg1[tid] = ws[WS_BG1 + tid];
  if (tid < 144) s_bg2[tid] = ws[WS_BG2 + tid];
  if (tid < 9)   s_C[tid]   = ws[WS_C9 + tid];
  for (int i = tid; i < 357; i += 256) s_w3j[i] = ws[i];
  { // x_scalar tile: 16*128 = 2048 elems, 8/thread
    int base = tid*8, row = base >> 7, col = base & 127;
    int n = n0 + row;
    if (n < N){
      if (isbf) load8_bf16((const u16*)xscv + (size_t)n*128 + col, &s_xs[row][col]);
      else      load8_f32 ((const float*)xscv + (size_t)n*128 + col, &s_xs[row][col]);
    } else { for (int q=0;q<8;q++) s_xs[row][col+q] = 0.f; }
  }
  { // x_spherical tile: 16*480 = 7680 elems
    for (int it = tid; it < 960; it += 256){
      int base = it*8, row = base/480, col = base - row*480;
      int n = n0 + row;
      if (n < N){
        if (isbf) load8_bf16((const u16*)xspv + (size_t)n*480 + col, &s_xsph[row][col]);
        else      load8_f32 ((const float*)xspv + (size_t)n*480 + col, &s_xsph[row][col]);
      } else { for (int q=0;q<8;q++) s_xsph[row][col+q] = 0.f; }
    }
  }
  __syncthreads();

  // ---- phase 1: h1 = silu(x_scalar @ Wg1 + bg1)
  {
    const int a0 = wave*4;
    float acc0=s_bg1[lane], acc1=acc0, acc2=acc0, acc3=acc0;
    for (int c=0;c<128;c++){
      float wv = wsWg1[c*64 + lane];
      acc0 += s_xs[a0+0][c]*wv;
      acc1 += s_xs[a0+1][c]*wv;
      acc2 += s_xs[a0+2][c]*wv;
      acc3 += s_xs[a0+3][c]*wv;
    }
    s_h1[a0+0][lane] = acc0/(1.f+__expf(-acc0));
    s_h1[a0+1][lane] = acc1/(1.f+__expf(-acc1));
    s_h1[a0+2][lane] = acc2/(1.f+__expf(-acc2));
    s_h1[a0+3][lane] = acc3/(1.f+__expf(-acc3));
  }
  __syncthreads();

  // ---- phase 2: w = h1 @ Wg2 + bg2
  {
    const int a0 = wave*4;
    float acc[4][3];
    #pragma unroll
    for (int t=0;t<4;t++){
      acc[t][0] = s_bg2[lane];
      acc[t][1] = s_bg2[64+lane];
      acc[t][2] = (lane<16) ? s_bg2[128+lane] : 0.f;
    }
    for (int c=0;c<64;c++){
      float w0 = wsWg2[c*144 + lane];
      float w1 = wsWg2[c*144 + 64 + lane];
      float w2 = (lane<16) ? wsWg2[c*144 + 128 + lane] : 0.f;
      #pragma unroll
      for (int t=0;t<4;t++){
        float h = s_h1[a0+t][c];
        acc[t][0] += h*w0; acc[t][1] += h*w1; acc[t][2] += h*w2;
      }
    }
    #pragma unroll
    for (int t=0;t<4;t++){
      s_w[a0+t][lane]    = acc[t][0];
      s_w[a0+t][64+lane] = acc[t][1];
      if (lane < 16) s_w[a0+t][128+lane] = acc[t][2];
    }
  }
  __syncthreads();

  // ---- phase 3: hU/hV = linear(x_spherical parts), thread -> (a, v)
  {
    const int a = tid >> 4, v = tid & 15;
    const float r128 = 0.088388347648318447f;
    const float r64  = 0.125f;
    const float r32  = 0.17677669529663689f;
    {
      float aU=0.f, aV=0.f;
      for (int u=0;u<128;u++){
        float x = s_xsph[a][u];
        aU += x*wsWU0[u*16+v];
        aV += x*wsWV0[u*16+v];
      }
      s_hU[a][v] = aU*r128; s_hV[a][v] = aV*r128;
    }
    {
      float aU[3]={0,0,0}, aV[3]={0,0,0};
      for (int u=0;u<64;u++){
        float wu = wsWU1[u*16+v], wv = wsWV1[u*16+v];
        #pragma unroll
        for (int i=0;i<3;i++){
          float x = s_xsph[a][128 + u*3 + i];
          aU[i] += x*wu; aV[i] += x*wv;
        }
      }
      #pragma unroll
      for (int i=0;i<3;i++){ s_hU[a][16+v*3+i]=aU[i]*r64; s_hV[a][16+v*3+i]=aV[i]*r64; }
    }
    {
      float aU[5]={0,0,0,0,0}, aV[5]={0,0,0,0,0};
      for (int u=0;u<32;u++){
        float wu = wsWU2[u*16+v], wv = wsWV2[u*16+v];
        #pragma unroll
        for (int i=0;i<5;i++){
          float x = s_xsph[a][320 + u*5 + i];
          aU[i] += x*wu; aV[i] += x*wv;
        }
      }
      #pragma unroll
      for (int i=0;i<5;i++){ s_hU[a][64+v*5+i]=aU[i]*r32; s_hV[a][64+v*5+i]=aV[i]*r32; }
    }
  }
  __syncthreads();

  // ---- phase 4: tensor products + u-reduction + segment atomicAdd --------
  {
    const int a = tid >> 4, u = tid & 15;
    float hu0 = s_hU[a][u], hv0 = s_hV[a][u];
    float hu1[3], hv1[3], hu2[5], hv2[5];
    #pragma unroll
    for (int i=0;i<3;i++){ hu1[i]=s_hU[a][16+u*3+i]; hv1[i]=s_hV[a][16+u*3+i]; }
    #pragma unroll
    for (int i=0;i<5;i++){ hu2[i]=s_hU[a][64+u*5+i]; hv2[i]=s_hV[a][64+u*5+i]; }
    float wk[9];
    #pragma unroll
    for (int k=0;k<9;k++) wk[k] = s_w[a][k*16+u];

    const float* J = s_w3j;
    float t9[9] = {0,0,0,0,0,0,0,0,0};

    t9[0] += s_C[0]*wk[0]*J[0]*hu0*hv0;
    {
      float cw = s_C[1]*wk[1]*hu0;
      #pragma unroll
      for (int m=0;m<5;m++){
        float s=0.f;
        #pragma unroll
        for (int j=0;j<5;j++) s += J[1 + j*5 + m]*hv2[j];
        t9[4+m] += cw*s;
      }
    }
    {
      float s=0.f;
      #pragma unroll
      for (int i=0;i<3;i++)
        #pragma unroll
        for (int j=0;j<3;j++) s += J[26 + i*3 + j]*hu1[i]*hv1[j];
      t9[0] += s_C[2]*wk[2]*s;
    }
    {
      float sm[3]={0,0,0};
      #pragma unroll
      for (int i=0;i<3;i++)
        #pragma unroll
        for (int j=0;j<3;j++){
          float p = hu1[i]*hv1[j];
          #pragma unroll
          for (int m=0;m<3;m++) sm[m] += J[35 + (i*3+j)*3 + m]*p;
        }
      float c = s_C[3]*wk[3];
      #pragma unroll
      for (int m=0;m<3;m++) t9[1+m] += c*sm[m];
    }
    {
      float sm[5]={0,0,0,0,0};
      #pragma unroll
      for (int i=0;i<3;i++)
        #pragma unroll
        for (int j=0;j<3;j++){
          float p = hu1[i]*hv1[j];
          #pragma unroll
          for (int m=0;m<5;m++) sm[m] += J[62 + (i*3+j)*5 + m]*p;
        }
      float c = s_C[4]*wk[4];
      #pragma unroll
      for (int m=0;m<5;m++) t9[4+m] += c*sm[m];
    }
    {
      float cw = s_C[5]*wk[5]*hv0;
      #pragma unroll
      for (int m=0;m<5;m++){
        float s=0.f;
        #pragma unroll
        for (int i=0;i<5;i++) s += J[107 + i*5 + m]*hu2[i];
        t9[4+m] += cw*s;
      }
    }
    {
      float s=0.f;
      #pragma unroll
      for (int i=0;i<5;i++)
        #pragma unroll
        for (int j=0;j<5;j++) s += J[132 + i*5 + j]*hu2[i]*hv2[j];
      t9[0] += s_C[6]*wk[6]*s;
    }
    {
      float sm[3]={0,0,0};
      #pragma unroll
      for (int i=0;i<5;i++)
        #pragma unroll
        for (int j=0;j<5;j++){
          float p = hu2[i]*hv2[j];
          #pragma unroll
          for (int m=0;m<3;m++) sm[m] += J[157 + (i*5+j)*3 + m]*p;
        }
      float c = s_C[7]*wk[7];
      #pragma unroll
      for (int m=0;m<3;m++) t9[1+m] += c*sm[m];
    }
    {
      float sm[5]={0,0,0,0,0};
      #pragma unroll
      for (int i=0;i<5;i++)
        #pragma unroll
        for (int j=0;j<5;j++){
          float p = hu2[i]*hv2[j];
          #pragma unroll
          for (int m=0;m<5;m++) sm[m] += J[232 + (i*5+j)*5 + m]*p;
        }
      float c = s_C[8]*wk[8];
      #pragma unroll
      for (int m=0;m<5;m++) t9[4+m] += c*sm[m];
    }

    #pragma unroll
    for (int mask=1; mask<16; mask<<=1){
      #pragma unroll
      for (int s=0;s<9;s++) t9[s] += __shfl_xor(t9[s], mask, 64);
    }
    if (u == 0 && (n0 + a) < N){
      int g = s_batch[a];
      float* r = res + (size_t)g*9;
      #pragma unroll
      for (int s=0;s<9;s++) atomicAdd(&r[s], t9[s]);
    }
  }
}

// ---------------------------------------------------------------------------
// Finish: res_sph (G x 9) -> out (G x 3 x 3) via Q_COB + CART permutation
// ---------------------------------------------------------------------------
__global__ void finish_kernel(const float* __restrict__ res,
                              const float* __restrict__ ws,
                              void* __restrict__ out, int G)
{
  int idx = blockIdx.x*256 + threadIdx.x;
  if (idx >= G*9) return;
  const int isbf = ((const int*)ws)[WS_FLAG];
  int g = idx/9, s = idx - g*9;
  int a = s/3, b = s - a*3;
  const int cart[3] = {2,0,1};
  int ca = cart[a], cb = cart[b];
  const float s3 = 1.7320508075688772f, s5 = 2.2360679774997896f;
  const float* r = res + (size_t)g*9;
  float acc = r[0]*ws[26 + ca*3 + cb];
  #pragma unroll
  for (int m=0;m<3;m++) acc += r[1+m]*s3*ws[35 + (ca*3+cb)*3 + m];
  #pragma unroll
  for (int m=0;m<5;m++) acc += r[4+m]*s5*ws[62 + (ca*3+cb)*5 + m];
  if (isbf) ((__hip_bfloat16*)out)[idx] = __float2bfloat16(acc);
  else      ((float*)out)[idx] = acc;
}

// ---------------------------------------------------------------------------
extern "C" void kernel_launch(void* const* d_in, const int* in_sizes, int n_in,
                              void* d_out, int out_size, void* d_ws, size_t ws_size,
                              hipStream_t stream) {
  const int* batch = (const int*)d_in[0];
  const void* xsc = d_in[1];
  const void* xsp = d_in[2];

  const int N = in_sizes[0];
  const int G = out_size / 9;

  float* ws  = (float*)d_ws;
  float* res = ws + WS_RES;

  hipMemsetAsync(res, 0, (size_t)G*9*sizeof(float), stream);
  detect_kernel<<<1, 64, 0, stream>>>((const u32*)xsp, (int*)(ws + WS_FLAG));
  setup_kernel<<<1, 64, 0, stream>>>(ws);
  convert_weights<<<11, 256, 0, stream>>>(d_in[9], d_in[11],
                                          d_in[3], d_in[4], d_in[5],
                                          d_in[6], d_in[7], d_in[8],
                                          d_in[10], d_in[12],
                                          d_in[13], d_in[14], d_in[15],
                                          ws);

  int nb = (N + TILE - 1) / TILE;
  main_kernel<<<nb, 256, 0, stream>>>(batch, xsc, xsp, ws, res, N);

  finish_kernel<<<(G*9 + 255)/256, 256, 0, stream>>>(res, ws, d_out, G);
}

// Round 3
// 1188.041 us; speedup vs baseline: 3.4621x; 3.4621x over previous
//
#include <hip/hip_runtime.h>
#include <hip/hip_bf16.h>
#include <math.h>

typedef unsigned short u16;
typedef unsigned int   u32;

#define TILE 16

// ---------------------------------------------------------------------------
// ws layout (float offsets):
//  [0..357)    : the 9 real-basis w3j tensors (see OFF[] below)
//  [368]       : dtype flag (int; 1 = inputs are bf16, 0 = inputs are f32)
//  [384..8576) : Wg1 f32   (8192)
//  [8576..)    : Wg2       (9216)
//  [17792..)   : WU0 (2048) [19840..): WU1 (1024) [20864..): WU2 (512)
//  [21376..)   : WV0 (2048) [23424..): WV1 (1024) [24448..): WV2 (512)
//  [24960..)   : bg1 (64)   [25024..): bg2 (144)  [25168..): C9 (9)
//  [25216..)   : res accumulator (G*9 f32)
// ---------------------------------------------------------------------------
#define WS_FLAG  368
#define WS_WG1   384
#define WS_WG2   8576
#define WS_WU0   17792
#define WS_WU1   19840
#define WS_WU2   20864
#define WS_WV0   21376
#define WS_WV1   23424
#define WS_WV2   24448
#define WS_BG1   24960
#define WS_BG2   25024
#define WS_C9    25168
#define WS_RES   25216

__device__ __forceinline__ float b2f(u16 u){
  return __uint_as_float(((u32)u) << 16);
}
__device__ __forceinline__ float ldconv(const void* p, int i, int isbf){
  return isbf ? b2f(((const u16*)p)[i]) : ((const float*)p)[i];
}

// ---------------------------------------------------------------------------
// dtype detection (see round-1 notes): bf16 buffers have sane exponent bits
// in the LOW u16 of each u32 word; f32 buffers have mantissa garbage there.
// ---------------------------------------------------------------------------
__global__ void detect_kernel(const u32* __restrict__ words, int* __restrict__ flag){
  int t = threadIdx.x;
  int cnt = 0;
  for (int i = 0; i < 16; i++){
    u32 w = words[t*16 + i];
    u32 e = (w >> 7) & 0xFF;
    cnt += (e >= 117 && e <= 137) ? 1 : 0;
  }
  #pragma unroll
  for (int m = 1; m < 64; m <<= 1) cnt += __shfl_xor(cnt, m, 64);
  if (t == 0) *flag = (cnt > 512) ? 1 : 0;
}

// ---------------------------------------------------------------------------
// Wigner 3j setup — parallel version: 9 blocks x 128 threads, one output
// element per lane, q-matrices in LDS (no per-thread arrays -> no scratch).
// ---------------------------------------------------------------------------
__device__ double factd(int n){ double r=1.0; for(int i=2;i<=n;++i) r*=(double)i; return r; }

__device__ double su2_cg(int j1,int m1,int j2,int m2,int j3,int m3){
  if (m1+m2 != m3) return 0.0;
  int vmin = max(max(-j1+j2+m3, -j1+m1), 0);
  int vmax = min(min(j2+j3+m1, j3-j1+j2), j3+m3);
  double C = sqrt((2.0*j3+1.0)
      * factd(j3+j1-j2)*factd(j3-j1+j2)*factd(j1+j2-j3)*factd(j3+m3)*factd(j3-m3)
      / (factd(j1+j2+j3+1)*factd(j1-m1)*factd(j1+m1)*factd(j2-m2)*factd(j2+m2)));
  double S = 0.0;
  for (int v=vmin; v<=vmax; ++v){
    double t = factd(j2+j3+m1-v)*factd(j1-m1+v)
             / (factd(v)*factd(j3-j1+j2-v)*factd(j3+m3-v)*factd(v+j1-j2-m3));
    S += ((v+j2+m2)&1) ? -t : t;
  }
  return C*S;
}

// q_real2complex(l) with the (-1j)^l prefactor, written into LDS arrays.
__device__ void qmat_lds(int l, double* qre, double* qim){
  int d = 2*l+1;
  for (int i=0;i<d*d;i++){ qre[i]=0.0; qim[i]=0.0; }
  double s = 1.0/sqrt(2.0);
  for (int m=-l; m<0; ++m){
    qre[(l+m)*d + (l-m)] = s;
    qim[(l+m)*d + (l+m)] = -s;
  }
  qre[l*d + l] = 1.0;
  for (int m=1; m<=l; ++m){
    double sgn = (m&1) ? -1.0 : 1.0;
    qre[(l+m)*d + (l+m)] = sgn*s;
    qim[(l+m)*d + (l-m)] = sgn*s;
  }
  double fr, fi;
  switch (l & 3){ case 0: fr=1; fi=0; break; case 1: fr=0; fi=-1; break;
                  case 2: fr=-1; fi=0; break; default: fr=0; fi=1; }
  for (int i=0;i<d*d;i++){
    double a=qre[i], b=qim[i];
    qre[i]=a*fr-b*fi; qim[i]=a*fi+b*fr;
  }
}

__global__ void setup_kernel(float* __restrict__ ws){
  __shared__ double q1r[25], q1i[25], q2r[25], q2i[25], q3r[25], q3i[25];
  __shared__ double red[128];
  const int L1[9]={0,0,1,1,1,2,2,2,2};
  const int L2[9]={0,2,1,1,1,0,2,2,2};
  const int L3[9]={0,2,0,1,2,2,0,1,2};
  const int OFF[9]={0,1,26,35,62,107,132,157,232};
  const int b = blockIdx.x;
  const int l1=L1[b], l2=L2[b], l3=L3[b];
  const int d1=2*l1+1, d2=2*l2+1, d3=2*l3+1;
  const int tot = d1*d2*d3;
  const int t = threadIdx.x;

  if (t==0) qmat_lds(l1, q1r, q1i);
  if (t==1) qmat_lds(l2, q2r, q2i);
  if (t==2) qmat_lds(l3, q3r, q3i);
  __syncthreads();

  double ar = 0.0;
  if (t < tot){
    const int j = t/(d2*d3), rem = t - j*(d2*d3), l = rem/d3, m = rem - l*d3;
    for (int i=0;i<d1;i++){
      double a1r=q1r[i*d1+j], a1i=q1i[i*d1+j];
      for (int k=0;k<d2;k++){
        double a2r=q2r[k*d2+l], a2i=q2i[k*d2+l];
        double t12r = a1r*a2r - a1i*a2i;
        double t12i = a1r*a2i + a1i*a2r;
        for (int n=0;n<d3;n++){
          double c = su2_cg(l1, i-l1, l2, k-l2, l3, n-l3);
          if (c==0.0) continue;
          double a3r = q3r[n*d3+m], a3i = -q3i[n*d3+m]; // conj
          ar += c*(t12r*a3r - t12i*a3i);
        }
      }
    }
  }
  red[t] = ar*ar;
  __syncthreads();
  for (int s=64; s>0; s>>=1){
    if (t < s) red[t] += red[t+s];
    __syncthreads();
  }
  double nrm = sqrt(red[0]);
  if (t < tot) ws[OFF[b] + t] = (float)(ar/nrm);
}

// ---------------------------------------------------------------------------
// Weight canonicalization: everything small -> f32 into ws
// ---------------------------------------------------------------------------
__global__ void convert_weights(
    const void* Wg1, const void* Wg2,
    const void* WU0, const void* WU1, const void* WU2,
    const void* WV0, const void* WV1, const void* WV2,
    const void* bg1, const void* bg2,
    const void* Wp0, const void* Wp1, const void* Wp2,
    float* __restrict__ ws)
{
  const int isbf = ((const int*)ws)[WS_FLAG];
  const int b = blockIdx.x, t = threadIdx.x;
  if (b < 10){
    const void* src[10] = {Wg1,Wg2,WU0,WU1,WU2,WV0,WV1,WV2,bg1,bg2};
    const int   sz[10]  = {8192,9216,2048,1024,512,2048,1024,512,64,144};
    const int   off[10] = {WS_WG1,WS_WG2,WS_WU0,WS_WU1,WS_WU2,WS_WV0,WS_WV1,WS_WV2,WS_BG1,WS_BG2};
    const void* s = src[b]; float* d = ws + off[b]; int n = sz[b];
    for (int i = t; i < n; i += 256) d[i] = ldconv(s, i, isbf);
  } else if (b == 10 && t == 0){
    float* C9 = ws + WS_C9;
    const int l3k[9]  = {0,2,0,1,2,2,0,1,2};
    const int idxk[9] = {0,0,1,0,1,2,2,1,3};
    for (int k=0;k<9;k++){
      int l3 = l3k[k];
      const void* wp = (l3==0) ? Wp0 : (l3==1) ? Wp1 : Wp2;
      float wpv = ldconv(wp, idxk[k], isbf);
      float len = (l3==0) ? 3.f : (l3==1) ? 2.f : 4.f;
      C9[k] = sqrtf((2.f*l3 + 1.f)/16.f) * wpv * rsqrtf(len);
    }
  }
}

// ---------------------------------------------------------------------------
// Main fused kernel: 16 atoms per block, 256 threads (4 waves).
// ---------------------------------------------------------------------------
__device__ __forceinline__ void load8_bf16(const u16* p, float* dst){
  uint4 v = *reinterpret_cast<const uint4*>(p);
  u32 w[4] = {v.x, v.y, v.z, v.w};
  #pragma unroll
  for (int q=0;q<4;q++){
    dst[2*q]   = __uint_as_float((w[q] & 0xffffu) << 16);
    dst[2*q+1] = __uint_as_float(w[q] & 0xffff0000u);
  }
}
__device__ __forceinline__ void load8_f32(const float* p, float* dst){
  float4 v0 = *reinterpret_cast<const float4*>(p);
  float4 v1 = *reinterpret_cast<const float4*>(p+4);
  dst[0]=v0.x; dst[1]=v0.y; dst[2]=v0.z; dst[3]=v0.w;
  dst[4]=v1.x; dst[5]=v1.y; dst[6]=v1.z; dst[7]=v1.w;
}

__global__ __launch_bounds__(256) void main_kernel(
    const int* __restrict__ batch,
    const void* __restrict__ xscv,   // N x 128 (bf16 or f32)
    const void* __restrict__ xspv,   // N x 480 (bf16 or f32)
    const float* __restrict__ ws,
    float* __restrict__ res,
    int N)
{
  __shared__ float s_xsph[TILE][481];
  __shared__ float s_w[TILE][144];
  __shared__ float s_uni[4624];
  __shared__ float s_w3j[357];
  __shared__ float s_bg1[64];
  __shared__ float s_bg2[144];
  __shared__ float s_C[9];
  __shared__ int   s_batch[TILE];

  float (*s_xs)[128] = reinterpret_cast<float(*)[128]>(s_uni);
  float (*s_h1)[64]  = reinterpret_cast<float(*)[64]>(s_uni + 2048);
  float (*s_hU)[144] = reinterpret_cast<float(*)[144]>(s_uni);
  float (*s_hV)[144] = reinterpret_cast<float(*)[144]>(s_uni + 2304);

  const int tid  = threadIdx.x;
  const int wave = tid >> 6;
  const int lane = tid & 63;
  const int n0   = blockIdx.x * TILE;
  const int isbf = ((const int*)ws)[WS_FLAG];

  const float* wsWg1 = ws + WS_WG1;
  const float* wsWg2 = ws + WS_WG2;
  const float* wsWU0 = ws + WS_WU0;
  const float* wsWU1 = ws + WS_WU1;
  const float* wsWU2 = ws + WS_WU2;
  const float* wsWV0 = ws + WS_WV0;
  const float* wsWV1 = ws + WS_WV1;
  const float* wsWV2 = ws + WS_WV2;

  // ---- staging -----------------------------------------------------------
  if (tid < TILE){ int n = n0 + tid; s_batch[tid] = (n < N) ? batch[n] : -1; }
  if (tid < 64)  s_bg1[tid] = ws[WS_BG1 + tid];
  if (tid < 144) s_bg2[tid] = ws[WS_BG2 + tid];
  if (tid < 9)   s_C[tid]   = ws[WS_C9 + tid];
  for (int i = tid; i < 357; i += 256) s_w3j[i] = ws[i];
  { // x_scalar tile: 16*128 = 2048 elems, 8/thread
    int base = tid*8, row = base >> 7, col = base & 127;
    int n = n0 + row;
    if (n < N){
      if (isbf) load8_bf16((const u16*)xscv + (size_t)n*128 + col, &s_xs[row][col]);
      else      load8_f32 ((const float*)xscv + (size_t)n*128 + col, &s_xs[row][col]);
    } else { for (int q=0;q<8;q++) s_xs[row][col+q] = 0.f; }
  }
  { // x_spherical tile: 16*480 = 7680 elems
    for (int it = tid; it < 960; it += 256){
      int base = it*8, row = base/480, col = base - row*480;
      int n = n0 + row;
      if (n < N){
        if (isbf) load8_bf16((const u16*)xspv + (size_t)n*480 + col, &s_xsph[row][col]);
        else      load8_f32 ((const float*)xspv + (size_t)n*480 + col, &s_xsph[row][col]);
      } else { for (int q=0;q<8;q++) s_xsph[row][col+q] = 0.f; }
    }
  }
  __syncthreads();

  // ---- phase 1: h1 = silu(x_scalar @ Wg1 + bg1)
  {
    const int a0 = wave*4;
    float acc0=s_bg1[lane], acc1=acc0, acc2=acc0, acc3=acc0;
    for (int c=0;c<128;c++){
      float wv = wsWg1[c*64 + lane];
      acc0 += s_xs[a0+0][c]*wv;
      acc1 += s_xs[a0+1][c]*wv;
      acc2 += s_xs[a0+2][c]*wv;
      acc3 += s_xs[a0+3][c]*wv;
    }
    s_h1[a0+0][lane] = acc0/(1.f+__expf(-acc0));
    s_h1[a0+1][lane] = acc1/(1.f+__expf(-acc1));
    s_h1[a0+2][lane] = acc2/(1.f+__expf(-acc2));
    s_h1[a0+3][lane] = acc3/(1.f+__expf(-acc3));
  }
  __syncthreads();

  // ---- phase 2: w = h1 @ Wg2 + bg2
  {
    const int a0 = wave*4;
    float acc[4][3];
    #pragma unroll
    for (int t=0;t<4;t++){
      acc[t][0] = s_bg2[lane];
      acc[t][1] = s_bg2[64+lane];
      acc[t][2] = (lane<16) ? s_bg2[128+lane] : 0.f;
    }
    for (int c=0;c<64;c++){
      float w0 = wsWg2[c*144 + lane];
      float w1 = wsWg2[c*144 + 64 + lane];
      float w2 = (lane<16) ? wsWg2[c*144 + 128 + lane] : 0.f;
      #pragma unroll
      for (int t=0;t<4;t++){
        float h = s_h1[a0+t][c];
        acc[t][0] += h*w0; acc[t][1] += h*w1; acc[t][2] += h*w2;
      }
    }
    #pragma unroll
    for (int t=0;t<4;t++){
      s_w[a0+t][lane]    = acc[t][0];
      s_w[a0+t][64+lane] = acc[t][1];
      if (lane < 16) s_w[a0+t][128+lane] = acc[t][2];
    }
  }
  __syncthreads();

  // ---- phase 3: hU/hV = linear(x_spherical parts), thread -> (a, v)
  {
    const int a = tid >> 4, v = tid & 15;
    const float r128 = 0.088388347648318447f;
    const float r64  = 0.125f;
    const float r32  = 0.17677669529663689f;
    {
      float aU=0.f, aV=0.f;
      for (int u=0;u<128;u++){
        float x = s_xsph[a][u];
        aU += x*wsWU0[u*16+v];
        aV += x*wsWV0[u*16+v];
      }
      s_hU[a][v] = aU*r128; s_hV[a][v] = aV*r128;
    }
    {
      float aU[3]={0,0,0}, aV[3]={0,0,0};
      for (int u=0;u<64;u++){
        float wu = wsWU1[u*16+v], wv = wsWV1[u*16+v];
        #pragma unroll
        for (int i=0;i<3;i++){
          float x = s_xsph[a][128 + u*3 + i];
          aU[i] += x*wu; aV[i] += x*wv;
        }
      }
      #pragma unroll
      for (int i=0;i<3;i++){ s_hU[a][16+v*3+i]=aU[i]*r64; s_hV[a][16+v*3+i]=aV[i]*r64; }
    }
    {
      float aU[5]={0,0,0,0,0}, aV[5]={0,0,0,0,0};
      for (int u=0;u<32;u++){
        float wu = wsWU2[u*16+v], wv = wsWV2[u*16+v];
        #pragma unroll
        for (int i=0;i<5;i++){
          float x = s_xsph[a][320 + u*5 + i];
          aU[i] += x*wu; aV[i] += x*wv;
        }
      }
      #pragma unroll
      for (int i=0;i<5;i++){ s_hU[a][64+v*5+i]=aU[i]*r32; s_hV[a][64+v*5+i]=aV[i]*r32; }
    }
  }
  __syncthreads();

  // ---- phase 4: tensor products + u-reduction + segment atomicAdd --------
  {
    const int a = tid >> 4, u = tid & 15;
    float hu0 = s_hU[a][u], hv0 = s_hV[a][u];
    float hu1[3], hv1[3], hu2[5], hv2[5];
    #pragma unroll
    for (int i=0;i<3;i++){ hu1[i]=s_hU[a][16+u*3+i]; hv1[i]=s_hV[a][16+u*3+i]; }
    #pragma unroll
    for (int i=0;i<5;i++){ hu2[i]=s_hU[a][64+u*5+i]; hv2[i]=s_hV[a][64+u*5+i]; }
    float wk[9];
    #pragma unroll
    for (int k=0;k<9;k++) wk[k] = s_w[a][k*16+u];

    const float* J = s_w3j;
    float t9[9] = {0,0,0,0,0,0,0,0,0};

    t9[0] += s_C[0]*wk[0]*J[0]*hu0*hv0;
    {
      float cw = s_C[1]*wk[1]*hu0;
      #pragma unroll
      for (int m=0;m<5;m++){
        float s=0.f;
        #pragma unroll
        for (int j=0;j<5;j++) s += J[1 + j*5 + m]*hv2[j];
        t9[4+m] += cw*s;
      }
    }
    {
      float s=0.f;
      #pragma unroll
      for (int i=0;i<3;i++)
        #pragma unroll
        for (int j=0;j<3;j++) s += J[26 + i*3 + j]*hu1[i]*hv1[j];
      t9[0] += s_C[2]*wk[2]*s;
    }
    {
      float sm[3]={0,0,0};
      #pragma unroll
      for (int i=0;i<3;i++)
        #pragma unroll
        for (int j=0;j<3;j++){
          float p = hu1[i]*hv1[j];
          #pragma unroll
          for (int m=0;m<3;m++) sm[m] += J[35 + (i*3+j)*3 + m]*p;
        }
      float c = s_C[3]*wk[3];
      #pragma unroll
      for (int m=0;m<3;m++) t9[1+m] += c*sm[m];
    }
    {
      float sm[5]={0,0,0,0,0};
      #pragma unroll
      for (int i=0;i<3;i++)
        #pragma unroll
        for (int j=0;j<3;j++){
          float p = hu1[i]*hv1[j];
          #pragma unroll
          for (int m=0;m<5;m++) sm[m] += J[62 + (i*3+j)*5 + m]*p;
        }
      float c = s_C[4]*wk[4];
      #pragma unroll
      for (int m=0;m<5;m++) t9[4+m] += c*sm[m];
    }
    {
      float cw = s_C[5]*wk[5]*hv0;
      #pragma unroll
      for (int m=0;m<5;m++){
        float s=0.f;
        #pragma unroll
        for (int i=0;i<5;i++) s += J[107 + i*5 + m]*hu2[i];
        t9[4+m] += cw*s;
      }
    }
    {
      float s=0.f;
      #pragma unroll
      for (int i=0;i<5;i++)
        #pragma unroll
        for (int j=0;j<5;j++) s += J[132 + i*5 + j]*hu2[i]*hv2[j];
      t9[0] += s_C[6]*wk[6]*s;
    }
    {
      float sm[3]={0,0,0};
      #pragma unroll
      for (int i=0;i<5;i++)
        #pragma unroll
        for (int j=0;j<5;j++){
          float p = hu2[i]*hv2[j];
          #pragma unroll
          for (int m=0;m<3;m++) sm[m] += J[157 + (i*5+j)*3 + m]*p;
        }
      float c = s_C[7]*wk[7];
      #pragma unroll
      for (int m=0;m<3;m++) t9[1+m] += c*sm[m];
    }
    {
      float sm[5]={0,0,0,0,0};
      #pragma unroll
      for (int i=0;i<5;i++)
        #pragma unroll
        for (int j=0;j<5;j++){
          float p = hu2[i]*hv2[j];
          #pragma unroll
          for (int m=0;m<5;m++) sm[m] += J[232 + (i*5+j)*5 + m]*p;
        }
      float c = s_C[8]*wk[8];
      #pragma unroll
      for (int m=0;m<5;m++) t9[4+m] += c*sm[m];
    }

    #pragma unroll
    for (int mask=1; mask<16; mask<<=1){
      #pragma unroll
      for (int s=0;s<9;s++) t9[s] += __shfl_xor(t9[s], mask, 64);
    }
    if (u == 0 && (n0 + a) < N){
      int g = s_batch[a];
      float* r = res + (size_t)g*9;
      #pragma unroll
      for (int s=0;s<9;s++) atomicAdd(&r[s], t9[s]);
    }
  }
}

// ---------------------------------------------------------------------------
// Finish: res_sph (G x 9) -> out (G x 3 x 3) via Q_COB + CART permutation
// ---------------------------------------------------------------------------
__global__ void finish_kernel(const float* __restrict__ res,
                              const float* __restrict__ ws,
                              void* __restrict__ out, int G)
{
  int idx = blockIdx.x*256 + threadIdx.x;
  if (idx >= G*9) return;
  const int isbf = ((const int*)ws)[WS_FLAG];
  int g = idx/9, s = idx - g*9;
  int a = s/3, b = s - a*3;
  const int cart[3] = {2,0,1};
  int ca = cart[a], cb = cart[b];
  const float s3 = 1.7320508075688772f, s5 = 2.2360679774997896f;
  const float* r = res + (size_t)g*9;
  float acc = r[0]*ws[26 + ca*3 + cb];
  #pragma unroll
  for (int m=0;m<3;m++) acc += r[1+m]*s3*ws[35 + (ca*3+cb)*3 + m];
  #pragma unroll
  for (int m=0;m<5;m++) acc += r[4+m]*s5*ws[62 + (ca*3+cb)*5 + m];
  if (isbf) ((__hip_bfloat16*)out)[idx] = __float2bfloat16(acc);
  else      ((float*)out)[idx] = acc;
}

// ---------------------------------------------------------------------------
extern "C" void kernel_launch(void* const* d_in, const int* in_sizes, int n_in,
                              void* d_out, int out_size, void* d_ws, size_t ws_size,
                              hipStream_t stream) {
  const int* batch = (const int*)d_in[0];
  const void* xsc = d_in[1];
  const void* xsp = d_in[2];

  const int N = in_sizes[0];
  const int G = out_size / 9;

  float* ws  = (float*)d_ws;
  float* res = ws + WS_RES;

  hipMemsetAsync(res, 0, (size_t)G*9*sizeof(float), stream);
  detect_kernel<<<1, 64, 0, stream>>>((const u32*)xsp, (int*)(ws + WS_FLAG));
  setup_kernel<<<9, 128, 0, stream>>>(ws);
  convert_weights<<<11, 256, 0, stream>>>(d_in[9], d_in[11],
                                          d_in[3], d_in[4], d_in[5],
                                          d_in[6], d_in[7], d_in[8],
                                          d_in[10], d_in[12],
                                          d_in[13], d_in[14], d_in[15],
                                          ws);

  int nb = (N + TILE - 1) / TILE;
  main_kernel<<<nb, 256, 0, stream>>>(batch, xsc, xsp, ws, res, N);

  finish_kernel<<<(G*9 + 255)/256, 256, 0, stream>>>(res, ws, d_out, G);
}